// Round 1
// baseline (2910.374 us; speedup 1.0000x reference)
//
#include <hip/hip_runtime.h>
#include <hip/hip_bf16.h>

// ---- fixed problem geometry ----
#define S 2048
#define D 1024
#define NH 16
#define HD 64
#define NL 4
#define VOCAB 32000
#define DFF 4096
#define EPS_LN 1e-5f

typedef __attribute__((ext_vector_type(8))) short short8;
typedef __attribute__((ext_vector_type(4))) float f32x4;

__device__ __forceinline__ unsigned short f2bf(float f) {
    unsigned u = __float_as_uint(f);
    u += 0x7FFFu + ((u >> 16) & 1u);   // round-to-nearest-even
    return (unsigned short)(u >> 16);
}

__device__ __forceinline__ short8 load8_bf(const float* p) {
    float4 v0 = *reinterpret_cast<const float4*>(p);
    float4 v1 = *reinterpret_cast<const float4*>(p + 4);
    short8 r;
    r[0] = (short)f2bf(v0.x); r[1] = (short)f2bf(v0.y);
    r[2] = (short)f2bf(v0.z); r[3] = (short)f2bf(v0.w);
    r[4] = (short)f2bf(v1.x); r[5] = (short)f2bf(v1.y);
    r[6] = (short)f2bf(v1.z); r[7] = (short)f2bf(v1.w);
    return r;
}

// ---------------- embedding + positional ----------------
__global__ __launch_bounds__(256) void embed_kernel(
    const int* __restrict__ ids, const float* __restrict__ embed,
    const float* __restrict__ pos, float* __restrict__ h)
{
    int i = blockIdx.x * 256 + threadIdx.x;     // grid exactly covers S*D
    int srow = i >> 10;                          // /D
    int d = i & (D - 1);
    h[i] = embed[(size_t)ids[srow] * D + d] + pos[i];
}

// ---------------- generic NT GEMM: C = A @ B^T + bias ----------------
// A: [M x K] f32 row-major (activations), B: [N x K] f32 row-major (weights, nn.Linear layout)
// 128x128 tile, BK=32, 256 threads (4 waves, each 64x64 via 4x4 16x16x32 MFMA frags)
template<int RELU, int HASBIAS>
__global__ __launch_bounds__(256) void gemm_nt(
    const float* __restrict__ A, const float* __restrict__ B,
    const float* __restrict__ bias, float* __restrict__ C,
    int M, int N, int K)
{
    __shared__ short As[128 * 32];
    __shared__ short Bs[128 * 32];
    const int tid = threadIdx.x;
    const int brow = blockIdx.y * 128;
    const int bcol = blockIdx.x * 128;
    const int wid = tid >> 6, lane = tid & 63;
    const int l15 = lane & 15, l4 = lane >> 4;
    const int wr = wid >> 1, wc = wid & 1;

    f32x4 acc[4][4] = {};

    // staging map: lane t -> row0 = t>>3 (0..31), col4 = (t&7)*4 ; 4 row-strides of 32
    const int r0 = tid >> 3;
    const int c4 = (tid & 7) * 4;

    const int nkb = K >> 5;
    for (int kb = 0; kb < nkb; ++kb) {
        const float* Ag = A + (size_t)(brow + r0) * K + kb * 32 + c4;
        const float* Bg = B + (size_t)(bcol + r0) * K + kb * 32 + c4;
        #pragma unroll
        for (int i = 0; i < 4; ++i) {
            float4 av = *reinterpret_cast<const float4*>(Ag + (size_t)(32 * i) * K);
            float4 bv = *reinterpret_cast<const float4*>(Bg + (size_t)(32 * i) * K);
            unsigned a0 = (unsigned)f2bf(av.x) | ((unsigned)f2bf(av.y) << 16);
            unsigned a1 = (unsigned)f2bf(av.z) | ((unsigned)f2bf(av.w) << 16);
            unsigned b0 = (unsigned)f2bf(bv.x) | ((unsigned)f2bf(bv.y) << 16);
            unsigned b1 = (unsigned)f2bf(bv.z) | ((unsigned)f2bf(bv.w) << 16);
            *reinterpret_cast<uint2*>(&As[(r0 + 32 * i) * 32 + c4]) = make_uint2(a0, a1);
            *reinterpret_cast<uint2*>(&Bs[(r0 + 32 * i) * 32 + c4]) = make_uint2(b0, b1);
        }
        __syncthreads();

        short8 af[4], bfr[4];
        #pragma unroll
        for (int rt = 0; rt < 4; ++rt)
            af[rt] = *reinterpret_cast<const short8*>(&As[(wr * 64 + rt * 16 + l15) * 32 + l4 * 8]);
        #pragma unroll
        for (int ct = 0; ct < 4; ++ct)
            bfr[ct] = *reinterpret_cast<const short8*>(&Bs[(wc * 64 + ct * 16 + l15) * 32 + l4 * 8]);
        #pragma unroll
        for (int rt = 0; rt < 4; ++rt)
            #pragma unroll
            for (int ct = 0; ct < 4; ++ct)
                acc[rt][ct] = __builtin_amdgcn_mfma_f32_16x16x32_bf16(af[rt], bfr[ct], acc[rt][ct], 0, 0, 0);
        __syncthreads();
    }

    // epilogue: C/D layout col = lane&15, row = (lane>>4)*4 + reg
    #pragma unroll
    for (int rt = 0; rt < 4; ++rt) {
        #pragma unroll
        for (int ct = 0; ct < 4; ++ct) {
            const int ccol = bcol + wc * 64 + ct * 16 + l15;
            float bv = HASBIAS ? bias[ccol] : 0.0f;
            #pragma unroll
            for (int j = 0; j < 4; ++j) {
                const int crow = brow + wr * 64 + rt * 16 + l4 * 4 + j;
                float v = acc[rt][ct][j] + bv;
                if (RELU) v = fmaxf(v, 0.0f);
                C[(size_t)crow * N + ccol] = v;
            }
        }
    }
}

// ---------------- flash attention (causal), f32 in/out, bf16 MFMA ----------------
// grid: (S/64, NH); block 256 = 4 waves; wave w handles q rows [q0+16w, q0+16w+16)
__global__ __launch_bounds__(256) void attn_kernel(
    const float* __restrict__ q, const float* __restrict__ k,
    const float* __restrict__ v, float* __restrict__ out)
{
    const int h = blockIdx.y;
    const int q0 = blockIdx.x * 64;
    const int tid = threadIdx.x;
    const int w = tid >> 6, lane = tid & 63;
    const int l15 = lane & 15, l4 = lane >> 4;
    const int qrow0 = q0 + w * 16;

    __shared__ short p_lds[4][16][48];   // per-wave P tile [16 x 32], stride 48 (16B-aligned rows)

    // Q A-frags (2 feature halves of HD=64)
    short8 aq[2];
    {
        const float* qp = q + (size_t)(qrow0 + l15) * D + h * HD + l4 * 8;
        aq[0] = load8_bf(qp);
        aq[1] = load8_bf(qp + 32);
    }

    f32x4 o[4] = {};
    float mrow[4], lrow[4];
    #pragma unroll
    for (int j = 0; j < 4; ++j) { mrow[j] = -1e30f; lrow[j] = 0.0f; }

    const int nkb = blockIdx.x * 2 + 2;   // covers keys 0 .. q0+63
    for (int kb32 = 0; kb32 < nkb; ++kb32) {
        const int kb = kb32 * 32;
        // S = Q K^T  (two 16-key halves, K-dim 64 = 2 MFMAs each)
        f32x4 s[2] = {};
        #pragma unroll
        for (int kh = 0; kh < 2; ++kh) {
            const float* kp = k + (size_t)(kb + kh * 16 + l15) * D + h * HD + l4 * 8;
            short8 b0 = load8_bf(kp);
            short8 b1 = load8_bf(kp + 32);
            s[kh] = __builtin_amdgcn_mfma_f32_16x16x32_bf16(aq[0], b0, s[kh], 0, 0, 0);
            s[kh] = __builtin_amdgcn_mfma_f32_16x16x32_bf16(aq[1], b1, s[kh], 0, 0, 0);
        }
        // scale + causal mask + online softmax (row r = l4*4+j lives in 16-lane group)
        float fac[4];
        #pragma unroll
        for (int j = 0; j < 4; ++j) {
            const int qg = qrow0 + l4 * 4 + j;
            float v0 = s[0][j] * 0.125f;
            float v1 = s[1][j] * 0.125f;
            if (kb + l15 > qg)      v0 = -1e30f;
            if (kb + 16 + l15 > qg) v1 = -1e30f;
            float bm = fmaxf(v0, v1);
            #pragma unroll
            for (int d_ = 1; d_ < 16; d_ <<= 1) bm = fmaxf(bm, __shfl_xor(bm, d_, 64));
            const float mnew = fmaxf(mrow[j], bm);
            const float f = __expf(mrow[j] - mnew);
            const float p0 = __expf(v0 - mnew);
            const float p1 = __expf(v1 - mnew);
            s[0][j] = p0; s[1][j] = p1;
            float rs = p0 + p1;
            #pragma unroll
            for (int d_ = 1; d_ < 16; d_ <<= 1) rs += __shfl_xor(rs, d_, 64);
            lrow[j] = lrow[j] * f + rs;
            mrow[j] = mnew;
            fac[j] = f;
        }
        #pragma unroll
        for (int c = 0; c < 4; ++c)
            #pragma unroll
            for (int j = 0; j < 4; ++j) o[c][j] *= fac[j];

        // P (D-layout) -> LDS -> A-fragment layout
        #pragma unroll
        for (int kh = 0; kh < 2; ++kh)
            #pragma unroll
            for (int j = 0; j < 4; ++j)
                p_lds[w][l4 * 4 + j][kh * 16 + l15] = (short)f2bf(s[kh][j]);
        __syncthreads();   // uniform trip count across waves; guards LDS RAW
        short8 pa = *reinterpret_cast<const short8*>(&p_lds[w][l15][l4 * 8]);

        // O += P @ V  (4 d-chunks of 16)
        #pragma unroll
        for (int c = 0; c < 4; ++c) {
            short8 bv;
            #pragma unroll
            for (int i = 0; i < 8; ++i)
                bv[i] = (short)f2bf(v[(size_t)(kb + l4 * 8 + i) * D + h * HD + c * 16 + l15]);
            o[c] = __builtin_amdgcn_mfma_f32_16x16x32_bf16(pa, bv, o[c], 0, 0, 0);
        }
        __syncthreads();
    }

    #pragma unroll
    for (int c = 0; c < 4; ++c)
        #pragma unroll
        for (int j = 0; j < 4; ++j)
            out[(size_t)(qrow0 + l4 * 4 + j) * D + h * HD + c * 16 + l15] = o[c][j] / lrow[j];
}

// ---------------- fused residual + LayerNorm: y = LN(a + b) * g + bb ----------------
__global__ __launch_bounds__(256) void ln_kernel(
    const float* __restrict__ a, const float* __restrict__ b,
    const float* __restrict__ g, const float* __restrict__ bb,
    float* __restrict__ y)
{
    const int row = blockIdx.x;
    const int tid = threadIdx.x;
    const size_t base = (size_t)row * D;
    float x[4]; float s = 0.f, s2 = 0.f;
    #pragma unroll
    for (int i = 0; i < 4; ++i) {
        const int c = tid + i * 256;
        x[i] = a[base + c] + b[base + c];
        s += x[i]; s2 += x[i] * x[i];
    }
    #pragma unroll
    for (int d_ = 1; d_ < 64; d_ <<= 1) {
        s  += __shfl_xor(s,  d_, 64);
        s2 += __shfl_xor(s2, d_, 64);
    }
    __shared__ float rs[4], rs2[4];
    const int wid = tid >> 6, lane = tid & 63;
    if (lane == 0) { rs[wid] = s; rs2[wid] = s2; }
    __syncthreads();
    s = rs[0] + rs[1] + rs[2] + rs[3];
    s2 = rs2[0] + rs2[1] + rs2[2] + rs2[3];
    const float mu = s * (1.0f / D);
    const float var = s2 * (1.0f / D) - mu * mu;
    const float inv = rsqrtf(var + EPS_LN);
    #pragma unroll
    for (int i = 0; i < 4; ++i) {
        const int c = tid + i * 256;
        y[base + c] = (x[i] - mu) * inv * g[c] + bb[c];
    }
}

// ---------------- launch ----------------
extern "C" void kernel_launch(void* const* d_in, const int* in_sizes, int n_in,
                              void* d_out, int out_size, void* d_ws, size_t ws_size,
                              hipStream_t stream) {
    const int*   ids   = (const int*)  d_in[0];
    const float* emb   = (const float*)d_in[1];
    const float* pos   = (const float*)d_in[2];
    const float* wq    = (const float*)d_in[3];
    const float* bq    = (const float*)d_in[4];
    const float* wk    = (const float*)d_in[5];
    const float* bk    = (const float*)d_in[6];
    const float* wv    = (const float*)d_in[7];
    const float* bv    = (const float*)d_in[8];
    const float* wo    = (const float*)d_in[9];
    const float* bo    = (const float*)d_in[10];
    const float* ln1g  = (const float*)d_in[11];
    const float* ln1b  = (const float*)d_in[12];
    const float* w1    = (const float*)d_in[13];
    const float* b1    = (const float*)d_in[14];
    const float* w2    = (const float*)d_in[15];
    const float* b2    = (const float*)d_in[16];
    const float* ln2g  = (const float*)d_in[17];
    const float* ln2b  = (const float*)d_in[18];
    const float* lmh   = (const float*)d_in[19];
    float* out = (float*)d_out;
    float* ws  = (float*)d_ws;

    const size_t SD = (size_t)S * D;            // 2 M floats = 8 MB
    float* h   = ws;                            // persistent hidden state
    float* qb  = ws + SD;                       // q, later reused as attn-proj output
    float* kbf = ws + 2 * SD;                   // k, later reused as h2 (post-LN1)
    float* vbf = ws + 3 * SD;                   // v, later reused as m2 (MLP out)
    float* att = ws + 4 * SD;                   // attention output
    float* m1  = ws + 5 * SD;                   // MLP hidden [S x DFF] = 32 MB
    // total ws use: 72 MB

    embed_kernel<<<(S * D) / 256, 256, 0, stream>>>(ids, emb, pos, h);

    const dim3 gemm_blk(256);
    const dim3 g_d (D / 128, S / 128);          // (8,16)
    const dim3 g_ff(DFF / 128, S / 128);        // (32,16)
    const dim3 g_lm(VOCAB / 128, S / 128);      // (250,16)

    for (int l = 0; l < NL; ++l) {
        const size_t wofs  = (size_t)l * D * D;
        const size_t w1ofs = (size_t)l * DFF * D;
        gemm_nt<0,1><<<g_d, gemm_blk, 0, stream>>>(h, wq + wofs, bq + l * D, qb,  S, D, D);
        gemm_nt<0,1><<<g_d, gemm_blk, 0, stream>>>(h, wk + wofs, bk + l * D, kbf, S, D, D);
        gemm_nt<0,1><<<g_d, gemm_blk, 0, stream>>>(h, wv + wofs, bv + l * D, vbf, S, D, D);

        attn_kernel<<<dim3(S / 64, NH), 256, 0, stream>>>(qb, kbf, vbf, att);

        gemm_nt<0,1><<<g_d, gemm_blk, 0, stream>>>(att, wo + wofs, bo + l * D, qb, S, D, D);  // o-proj (qb reused)
        ln_kernel<<<S, 256, 0, stream>>>(h, qb, ln1g + l * D, ln1b + l * D, kbf);             // h2 = LN(h+o) -> kbf

        gemm_nt<1,1><<<g_ff, gemm_blk, 0, stream>>>(kbf, w1 + w1ofs, b1 + l * DFF, m1, S, DFF, D);   // relu
        gemm_nt<0,1><<<g_d,  gemm_blk, 0, stream>>>(m1,  w2 + w1ofs, b2 + l * D,   vbf, S, D, DFF);
        ln_kernel<<<S, 256, 0, stream>>>(kbf, vbf, ln2g + l * D, ln2b + l * D, h);            // h = LN(h2+m2)
    }

    gemm_nt<0,0><<<g_lm, gemm_blk, 0, stream>>>(h, lmh, nullptr, out, S, VOCAB, D);
}

// Round 4
// 1503.529 us; speedup vs baseline: 1.9357x; 1.9357x over previous
//
#include <hip/hip_runtime.h>
#include <hip/hip_bf16.h>

// ---- fixed problem geometry ----
#define S 2048
#define D 1024
#define NH 16
#define HD 64
#define NL 4
#define VOCAB 32000
#define DFF 4096
#define EPS_LN 1e-5f

typedef unsigned short ushortT;
typedef __attribute__((ext_vector_type(8))) short short8;
typedef __attribute__((ext_vector_type(4))) unsigned short ushort4v;
typedef __attribute__((ext_vector_type(4))) float f32x4;

__device__ __forceinline__ ushortT f2bf(float f) {
    unsigned u = __float_as_uint(f);
    u += 0x7FFFu + ((u >> 16) & 1u);   // round-to-nearest-even
    return (ushortT)(u >> 16);
}

// async global->LDS, 16 bytes per lane; LDS dest must be wave-uniform base + lane*16
__device__ __forceinline__ void gload_lds16(const ushortT* g, ushortT* l) {
    auto gp = (const __attribute__((address_space(1))) unsigned int*)(uintptr_t)g;
    auto lp = (__attribute__((address_space(3))) unsigned int*)(uintptr_t)l;
    __builtin_amdgcn_global_load_lds(gp, lp, 16, 0, 0);
}

__device__ __forceinline__ void cvt8(const float* s, ushortT* d) {
    float4 a = *(const float4*)s;
    float4 b = *(const float4*)(s + 4);
    short8 r;
    r[0] = (short)f2bf(a.x); r[1] = (short)f2bf(a.y);
    r[2] = (short)f2bf(a.z); r[3] = (short)f2bf(a.w);
    r[4] = (short)f2bf(b.x); r[5] = (short)f2bf(b.y);
    r[6] = (short)f2bf(b.z); r[7] = (short)f2bf(b.w);
    *(short8*)d = r;
}

// ---------------- embedding + positional (dual f32/bf16 out) ----------------
__global__ __launch_bounds__(256) void embed_kernel(
    const int* __restrict__ ids, const float* __restrict__ embed,
    const float* __restrict__ pos, float* __restrict__ hf, ushortT* __restrict__ hb)
{
    int i = blockIdx.x * 256 + threadIdx.x;
    int srow = i >> 10;
    int d = i & (D - 1);
    float v = embed[(size_t)ids[srow] * D + d] + pos[i];
    hf[i] = v;
    hb[i] = f2bf(v);
}

// ---------------- per-layer weight conversion f32 -> bf16 (packed) ----------------
// dst layout (ushort elements): wqkv [3D*D] | wo [D*D] | w1 [4D*D] | w2 [4D*D]; bias qkv packed f32 [3D]
__global__ __launch_bounds__(256) void convert_layer(
    const float* __restrict__ wq, const float* __restrict__ wk, const float* __restrict__ wv,
    const float* __restrict__ wo, const float* __restrict__ w1, const float* __restrict__ w2,
    const float* __restrict__ bq, const float* __restrict__ bk, const float* __restrict__ bv,
    int l, ushortT* __restrict__ wl, float* __restrict__ bqkv)
{
    constexpr int R = (D * D) / 8;   // 131072 units of 8 elements
    const int u = blockIdx.x * 256 + threadIdx.x;
    if (u < 12 * R) {
        const float* src;
        if (u < 3 * R) {
            int sub = u >> 17, off = u & (R - 1);
            const float* w = (sub == 0) ? wq : (sub == 1) ? wk : wv;
            src = w + (size_t)l * D * D + (size_t)off * 8;
        } else if (u < 4 * R) {
            src = wo + (size_t)l * D * D + (size_t)(u - 3 * R) * 8;
        } else if (u < 8 * R) {
            src = w1 + (size_t)l * 4 * D * D + (size_t)(u - 4 * R) * 8;
        } else {
            src = w2 + (size_t)l * 4 * D * D + (size_t)(u - 8 * R) * 8;
        }
        cvt8(src, wl + (size_t)u * 8);
    } else if (u < 12 * R + 384) {
        int i = u - 12 * R;
        int sub = i >> 7, off = (i & 127) * 8;
        const float* src = ((sub == 0) ? bq : (sub == 1) ? bk : bv) + (size_t)l * D + off;
        *(float4*)(bqkv + sub * D + off)     = *(const float4*)src;
        *(float4*)(bqkv + sub * D + off + 4) = *(const float4*)(src + 4);
    }
}

__global__ __launch_bounds__(256) void convert_flat(
    const float* __restrict__ src, ushortT* __restrict__ dst)
{
    const size_t u = (size_t)blockIdx.x * 256 + threadIdx.x;   // grid exactly covers n/8
    cvt8(src + u * 8, dst + u * 8);
}

// ---------------- bf16 NT GEMM: C = A @ B^T + bias ----------------
// A [M x K], B [N x K] bf16 row-major. 128xBN tile, BK=32, 256 thr (4 waves).
// Block decode: mb = id & 15 (fastest -> weight-panel reuse), nb = id >> 4.
// OUTMODE: 0 = f32 out, 1 = bf16 out, 2 = fused QKV (q,k normal bf16 stride 2048; v transposed [D][S])
template<int BN, int OUTMODE, int RELU, int HASBIAS>
__global__ __launch_bounds__(256) void gemm_bf(
    const ushortT* __restrict__ A, const ushortT* __restrict__ B,
    const float* __restrict__ bias, void* __restrict__ Cn, void* __restrict__ Ct,
    int N, int K)
{
    constexpr int WN = BN / 2;
    constexpr int NCT = WN / 16;
    __shared__ alignas(16) ushortT As[128 * 32];
    __shared__ alignas(16) ushortT Bs[BN * 32];

    const int tid = threadIdx.x;
    const int id = blockIdx.x;
    const int brow = (id & 15) * 128;
    const int bcol = (id >> 4) * BN;
    const int lane = tid & 63, wid = tid >> 6;
    const int l15 = lane & 15, l4 = lane >> 4;
    const int wr = wid >> 1, wc = wid & 1;
    const int str = tid >> 2;            // staging row 0..63
    const int stc = (tid & 3) * 8;       // staging col (elements)

    f32x4 acc[4][NCT] = {};

    const ushortT* Ab = A + (size_t)(brow + str) * K + stc;
    const ushortT* Bb = B + (size_t)(bcol + str) * K + stc;
    ushortT* AsD = &As[tid * 8];
    ushortT* BsD = &Bs[tid * 8];

    const int nkb = K >> 5;
    for (int kb = 0; kb < nkb; ++kb) {
        const int ko = kb * 32;
        gload_lds16(Ab + ko, AsD);
        gload_lds16(Ab + ko + (size_t)64 * K, AsD + 2048);
        gload_lds16(Bb + ko, BsD);
        if (BN == 128) gload_lds16(Bb + ko + (size_t)64 * K, BsD + 2048);
        __syncthreads();

        short8 af[4], bfr[NCT];
        #pragma unroll
        for (int rt = 0; rt < 4; ++rt)
            af[rt] = *(const short8*)&As[(wr * 64 + rt * 16 + l15) * 32 + l4 * 8];
        #pragma unroll
        for (int ct = 0; ct < NCT; ++ct)
            bfr[ct] = *(const short8*)&Bs[(wc * WN + ct * 16 + l15) * 32 + l4 * 8];
        #pragma unroll
        for (int rt = 0; rt < 4; ++rt)
            #pragma unroll
            for (int ct = 0; ct < NCT; ++ct)
                acc[rt][ct] = __builtin_amdgcn_mfma_f32_16x16x32_bf16(af[rt], bfr[ct], acc[rt][ct], 0, 0, 0);
        __syncthreads();
    }

    // epilogue: C/D layout col = lane&15, row = (lane>>4)*4 + reg
    #pragma unroll
    for (int rt = 0; rt < 4; ++rt) {
        const int crow0 = brow + wr * 64 + rt * 16 + l4 * 4;
        #pragma unroll
        for (int ct = 0; ct < NCT; ++ct) {
            const int ccol = bcol + wc * WN + ct * 16 + l15;
            const float bv = HASBIAS ? bias[ccol] : 0.0f;
            if (OUTMODE == 0) {
                float* C = (float*)Cn;
                #pragma unroll
                for (int j = 0; j < 4; ++j) {
                    float v = acc[rt][ct][j] + bv;
                    if (RELU) v = fmaxf(v, 0.0f);
                    C[(size_t)(crow0 + j) * N + ccol] = v;
                }
            } else if (OUTMODE == 1) {
                ushortT* C = (ushortT*)Cn;
                #pragma unroll
                for (int j = 0; j < 4; ++j) {
                    float v = acc[rt][ct][j] + bv;
                    if (RELU) v = fmaxf(v, 0.0f);
                    C[(size_t)(crow0 + j) * N + ccol] = f2bf(v);
                }
            } else {
                if (bcol < 2048) {   // q,k region -> [S][2048]
                    ushortT* C = (ushortT*)Cn;
                    #pragma unroll
                    for (int j = 0; j < 4; ++j)
                        C[(size_t)(crow0 + j) * 2048 + ccol] = f2bf(acc[rt][ct][j] + bv);
                } else {             // v region -> transposed [D][S]
                    ushortT* C = (ushortT*)Ct;
                    ushort4v wv_;
                    #pragma unroll
                    for (int j = 0; j < 4; ++j) wv_[j] = f2bf(acc[rt][ct][j] + bv);
                    *(ushort4v*)&C[(size_t)(ccol - 2048) * S + crow0] = wv_;
                }
            }
        }
    }
}

// ---------------- flash attention (causal), bf16 in/out ----------------
// qk: [S][2048] (q cols 0..1023, k cols 1024..2047); vt: [1024][S] transposed V
// grid (S/64, NH); 4 waves, wave w owns q rows [q0+16w, q0+16w+16)
__global__ __launch_bounds__(256) void attn_kernel(
    const ushortT* __restrict__ qk, const ushortT* __restrict__ vt,
    ushortT* __restrict__ att)
{
    const int h = blockIdx.y;
    const int q0 = blockIdx.x * 64;
    const int tid = threadIdx.x;
    const int w = tid >> 6, lane = tid & 63;
    const int l15 = lane & 15, l4 = lane >> 4;
    const int qrow0 = q0 + w * 16;

    __shared__ short p_lds[4][16][48];

    short8 aq[2];
    {
        const ushortT* qp = qk + (size_t)(qrow0 + l15) * 2048 + h * HD + l4 * 8;
        aq[0] = *(const short8*)qp;
        aq[1] = *(const short8*)(qp + 32);
    }

    f32x4 o[4] = {};
    float mrow[4], lrow[4];
    #pragma unroll
    for (int j = 0; j < 4; ++j) { mrow[j] = -1e30f; lrow[j] = 0.0f; }

    const int nkb = blockIdx.x * 2 + 2;
    for (int kb32 = 0; kb32 < nkb; ++kb32) {
        const int kb = kb32 * 32;
        f32x4 s[2] = {};
        #pragma unroll
        for (int kh = 0; kh < 2; ++kh) {
            const ushortT* kp = qk + (size_t)(kb + kh * 16 + l15) * 2048 + 1024 + h * HD + l4 * 8;
            short8 b0 = *(const short8*)kp;
            short8 b1 = *(const short8*)(kp + 32);
            s[kh] = __builtin_amdgcn_mfma_f32_16x16x32_bf16(aq[0], b0, s[kh], 0, 0, 0);
            s[kh] = __builtin_amdgcn_mfma_f32_16x16x32_bf16(aq[1], b1, s[kh], 0, 0, 0);
        }
        float fac[4];
        #pragma unroll
        for (int j = 0; j < 4; ++j) {
            const int qg = qrow0 + l4 * 4 + j;
            float v0 = s[0][j] * 0.125f;
            float v1 = s[1][j] * 0.125f;
            if (kb + l15 > qg)      v0 = -1e30f;
            if (kb + 16 + l15 > qg) v1 = -1e30f;
            float bm = fmaxf(v0, v1);
            #pragma unroll
            for (int d_ = 1; d_ < 16; d_ <<= 1) bm = fmaxf(bm, __shfl_xor(bm, d_, 64));
            const float mnew = fmaxf(mrow[j], bm);
            const float f = __expf(mrow[j] - mnew);
            const float p0 = __expf(v0 - mnew);
            const float p1 = __expf(v1 - mnew);
            s[0][j] = p0; s[1][j] = p1;
            float rs = p0 + p1;
            #pragma unroll
            for (int d_ = 1; d_ < 16; d_ <<= 1) rs += __shfl_xor(rs, d_, 64);
            lrow[j] = lrow[j] * f + rs;
            mrow[j] = mnew;
            fac[j] = f;
        }
        #pragma unroll
        for (int c = 0; c < 4; ++c)
            #pragma unroll
            for (int j = 0; j < 4; ++j) o[c][j] *= fac[j];

        #pragma unroll
        for (int kh = 0; kh < 2; ++kh)
            #pragma unroll
            for (int j = 0; j < 4; ++j)
                p_lds[w][l4 * 4 + j][kh * 16 + l15] = (short)f2bf(s[kh][j]);
        __syncthreads();
        short8 pa = *(const short8*)&p_lds[w][l15][l4 * 8];

        #pragma unroll
        for (int c = 0; c < 4; ++c) {
            short8 bv = *(const short8*)(vt + (size_t)(h * HD + c * 16 + l15) * S + kb + l4 * 8);
            o[c] = __builtin_amdgcn_mfma_f32_16x16x32_bf16(pa, bv, o[c], 0, 0, 0);
        }
        __syncthreads();
    }

    #pragma unroll
    for (int c = 0; c < 4; ++c)
        #pragma unroll
        for (int j = 0; j < 4; ++j)
            att[(size_t)(qrow0 + l4 * 4 + j) * D + h * HD + c * 16 + l15] = f2bf(o[c][j] / lrow[j]);
}

// ---------------- fused residual + LayerNorm, dual f32/bf16 out ----------------
__global__ __launch_bounds__(256) void ln_kernel(
    const float* __restrict__ a, const float* __restrict__ b,
    const float* __restrict__ g, const float* __restrict__ bb,
    float* __restrict__ yf, ushortT* __restrict__ yb)
{
    const int row = blockIdx.x;
    const int tid = threadIdx.x;
    const size_t base = (size_t)row * D;
    float x[4]; float s = 0.f, s2 = 0.f;
    #pragma unroll
    for (int i = 0; i < 4; ++i) {
        const int c = tid + i * 256;
        x[i] = a[base + c] + b[base + c];
        s += x[i]; s2 += x[i] * x[i];
    }
    #pragma unroll
    for (int d_ = 1; d_ < 64; d_ <<= 1) {
        s  += __shfl_xor(s,  d_, 64);
        s2 += __shfl_xor(s2, d_, 64);
    }
    __shared__ float rs[4], rs2[4];
    const int wid = tid >> 6, lane = tid & 63;
    if (lane == 0) { rs[wid] = s; rs2[wid] = s2; }
    __syncthreads();
    s = rs[0] + rs[1] + rs[2] + rs[3];
    s2 = rs2[0] + rs2[1] + rs2[2] + rs2[3];
    const float mu = s * (1.0f / D);
    const float var = s2 * (1.0f / D) - mu * mu;
    const float inv = rsqrtf(var + EPS_LN);
    #pragma unroll
    for (int i = 0; i < 4; ++i) {
        const int c = tid + i * 256;
        float v = (x[i] - mu) * inv * g[c] + bb[c];
        yf[base + c] = v;
        yb[base + c] = f2bf(v);
    }
}

// ---------------- launch ----------------
extern "C" void kernel_launch(void* const* d_in, const int* in_sizes, int n_in,
                              void* d_out, int out_size, void* d_ws, size_t ws_size,
                              hipStream_t stream) {
    const int*   ids   = (const int*)  d_in[0];
    const float* emb   = (const float*)d_in[1];
    const float* pos   = (const float*)d_in[2];
    const float* wq    = (const float*)d_in[3];
    const float* bq    = (const float*)d_in[4];
    const float* wk    = (const float*)d_in[5];
    const float* bk    = (const float*)d_in[6];
    const float* wv    = (const float*)d_in[7];
    const float* bv    = (const float*)d_in[8];
    const float* wo    = (const float*)d_in[9];
    const float* bo    = (const float*)d_in[10];
    const float* ln1g  = (const float*)d_in[11];
    const float* ln1b  = (const float*)d_in[12];
    const float* w1    = (const float*)d_in[13];
    const float* b1    = (const float*)d_in[14];
    const float* w2    = (const float*)d_in[15];
    const float* b2    = (const float*)d_in[16];
    const float* ln2g  = (const float*)d_in[17];
    const float* ln2b  = (const float*)d_in[18];
    const float* lmh   = (const float*)d_in[19];
    float* out = (float*)d_out;

    const size_t MB = 1024 * 1024;
    char* w = (char*)d_ws;
    float*   h_f32   = (float*)(w);              //  8 MB  residual stream
    float*   h2_f32  = (float*)(w +  8 * MB);    //  8 MB  post-LN1 residual
    float*   om2_f32 = (float*)(w + 16 * MB);    //  8 MB  o-proj out, then MLP2 out
    ushortT* h_bf    = (ushortT*)(w + 24 * MB);  //  4 MB
    ushortT* h2_bf   = (ushortT*)(w + 28 * MB);  //  4 MB
    ushortT* qk_bf   = (ushortT*)(w + 32 * MB);  //  8 MB  [S][2048]
    ushortT* vt_bf   = (ushortT*)(w + 40 * MB);  //  4 MB  [1024][S]
    ushortT* att_bf  = (ushortT*)(w + 44 * MB);  //  4 MB
    ushortT* m1_bf   = (ushortT*)(w + 48 * MB);  // 16 MB  [S][4096]
    ushortT* wl      = (ushortT*)(w + 64 * MB);  // 24 MB  per-layer bf16 weights
    float*   bqkv    = (float*)(w + 88 * MB);    // 12 KB  packed qkv bias
    ushortT* lmh_bf  = (ushortT*)(w + 89 * MB);  // 65.5 MB

    ushortT* wqkv_bf = wl;
    ushortT* wo_bf   = wl + (size_t)3 * D * D;
    ushortT* w1_bf   = wl + (size_t)4 * D * D;
    ushortT* w2_bf   = wl + (size_t)8 * D * D;

    embed_kernel<<<(S * D) / 256, 256, 0, stream>>>(ids, emb, pos, h_f32, h_bf);

    for (int l = 0; l < NL; ++l) {
        convert_layer<<<6146, 256, 0, stream>>>(wq, wk, wv, wo, w1, w2, bq, bk, bv, l, wl, bqkv);

        // fused QKV: [S x 3072] = h_bf @ wqkv^T ; q,k -> qk_bf, v -> vt_bf (transposed)
        gemm_bf<128, 2, 0, 1><<<16 * 24, 256, 0, stream>>>(h_bf, wqkv_bf, bqkv, qk_bf, vt_bf, 3072, D);

        attn_kernel<<<dim3(S / 64, NH), 256, 0, stream>>>(qk_bf, vt_bf, att_bf);

        gemm_bf<64, 0, 0, 1><<<16 * 16, 256, 0, stream>>>(att_bf, wo_bf, bo + (size_t)l * D, om2_f32, nullptr, D, D);
        ln_kernel<<<S, 256, 0, stream>>>(h_f32, om2_f32, ln1g + (size_t)l * D, ln1b + (size_t)l * D, h2_f32, h2_bf);

        gemm_bf<128, 1, 1, 1><<<16 * 32, 256, 0, stream>>>(h2_bf, w1_bf, b1 + (size_t)l * DFF, m1_bf, nullptr, DFF, D);
        gemm_bf<64, 0, 0, 1><<<16 * 16, 256, 0, stream>>>(m1_bf, w2_bf, b2 + (size_t)l * D, om2_f32, nullptr, D, DFF);
        ln_kernel<<<S, 256, 0, stream>>>(h2_f32, om2_f32, ln2g + (size_t)l * D, ln2b + (size_t)l * D, h_f32, h_bf);
    }

    convert_flat<<<(VOCAB * D) / (256 * 8), 256, 0, stream>>>(lmh, lmh_bf);
    gemm_bf<128, 0, 0, 0><<<16 * 250, 256, 0, stream>>>(h_bf, lmh_bf, nullptr, out, nullptr, VOCAB, D);
}